// Round 1
// baseline (2101.541 us; speedup 1.0000x reference)
//
#include <hip/hip_runtime.h>
#include <math.h>

#define BB   4
#define SS   4096
#define DD   1024
#define BL   128
#define NB   32

// ---------------- fp32 tiled GEMM: C[M][N] = A[M][K] @ W[K][N] + bias[N] ----------------
// BM=BN=64, BK=16, 256 threads, 4x4 micro-tile per thread.
template<int BM, int BN, int BK>
__global__ __launch_bounds__(256)
void gemm_bias_f32(const float* __restrict__ A, const float* __restrict__ W,
                   const float* __restrict__ bias, float* __restrict__ C,
                   int M, int N, int K)
{
    __shared__ float As[BK][BM];   // transposed A tile: As[k][m]
    __shared__ float Bs[BK][BN];

    const int t  = threadIdx.x;
    const int tx = t & 15;         // N-dir
    const int ty = t >> 4;         // M-dir
    const int m0 = blockIdx.y * BM;
    const int n0 = blockIdx.x * BN;

    // A tile load mapping: 64 rows x 16 cols = 256 float4; thread -> (row=t/4, colgrp=t%4)
    const int ar = t >> 2;
    const int ac = (t & 3) * 4;
    // B tile load mapping: 16 rows x 64 cols; thread -> (row=t/16, colgrp=t%16)
    const int br = t >> 4;
    const int bc = (t & 15) * 4;

    const float* Aptr = A + (size_t)(m0 + ar) * K + ac;
    const float* Wptr = W + (size_t)br * N + (n0 + bc);

    float acc[4][4] = {};

    for (int k0 = 0; k0 < K; k0 += BK) {
        float4 a4 = *(const float4*)(Aptr + k0);
        float4 b4 = *(const float4*)(Wptr + (size_t)k0 * N);
        As[ac + 0][ar] = a4.x;
        As[ac + 1][ar] = a4.y;
        As[ac + 2][ar] = a4.z;
        As[ac + 3][ar] = a4.w;
        *(float4*)&Bs[br][bc] = b4;
        __syncthreads();
        #pragma unroll
        for (int kk = 0; kk < BK; ++kk) {
            float4 av = *(const float4*)&As[kk][ty * 4];
            float4 bv = *(const float4*)&Bs[kk][tx * 4];
            acc[0][0] += av.x * bv.x; acc[0][1] += av.x * bv.y; acc[0][2] += av.x * bv.z; acc[0][3] += av.x * bv.w;
            acc[1][0] += av.y * bv.x; acc[1][1] += av.y * bv.y; acc[1][2] += av.y * bv.z; acc[1][3] += av.y * bv.w;
            acc[2][0] += av.z * bv.x; acc[2][1] += av.z * bv.y; acc[2][2] += av.z * bv.z; acc[2][3] += av.z * bv.w;
            acc[3][0] += av.w * bv.x; acc[3][1] += av.w * bv.y; acc[3][2] += av.w * bv.z; acc[3][3] += av.w * bv.w;
        }
        __syncthreads();
    }

    #pragma unroll
    for (int i = 0; i < 4; ++i) {
        const int row = m0 + ty * 4 + i;
        const int col = n0 + tx * 4;
        float4 o;
        o.x = acc[i][0] + bias[col + 0];
        o.y = acc[i][1] + bias[col + 1];
        o.z = acc[i][2] + bias[col + 2];
        o.w = acc[i][3] + bias[col + 3];
        *(float4*)(C + (size_t)row * N + col) = o;
    }
}

// ---------------- column attention ----------------
// One block per (b, bl). L = NB = 32 over the block axis, head dim D = 1024, causal.
// qkv layout: ((b*NB + nb)*BL + bl)*3D + c ; q at c<D, k at D..2D, v at 2D..3D.
// out layout: ((b*NB + nb)*BL + bl)*D + d  == (B,S,D) row-major.
__global__ __launch_bounds__(256)
void col_attn(const float* __restrict__ qkv, float* __restrict__ out)
{
    const int b  = blockIdx.x >> 7;     // /BL
    const int bl = blockIdx.x & (BL - 1);

    __shared__ float q_s[NB][65];       // +1 pad: conflict-free strided reads
    __shared__ float k_s[NB][65];
    __shared__ float p_s[NB][NB + 1];   // scores -> probs

    const int t   = threadIdx.x;
    const int si  = t >> 3;             // 0..31 (score row)
    const int sj0 = (t & 7) * 4;        // score col group

    const size_t rowstride = (size_t)BL * 3 * DD;    // nb -> nb+1
    const float* base = qkv + ((size_t)b * NB * BL + bl) * (3 * DD);

    float sacc[4] = {0.f, 0.f, 0.f, 0.f};

    for (int d0 = 0; d0 < DD; d0 += 64) {
        // stage q,k chunk: 32 rows x 64 cols each (512 float4 -> 2 per thread)
        #pragma unroll
        for (int e = 0; e < 2; ++e) {
            const int f   = t + e * 256;
            const int row = f >> 4;
            const int cg  = (f & 15) * 4;
            float4 qv = *(const float4*)(base + (size_t)row * rowstride + d0 + cg);
            float4 kv = *(const float4*)(base + (size_t)row * rowstride + DD + d0 + cg);
            q_s[row][cg + 0] = qv.x; q_s[row][cg + 1] = qv.y; q_s[row][cg + 2] = qv.z; q_s[row][cg + 3] = qv.w;
            k_s[row][cg + 0] = kv.x; k_s[row][cg + 1] = kv.y; k_s[row][cg + 2] = kv.z; k_s[row][cg + 3] = kv.w;
        }
        __syncthreads();
        #pragma unroll
        for (int d = 0; d < 64; ++d) {
            const float qv = q_s[si][d];
            sacc[0] += qv * k_s[sj0 + 0][d];
            sacc[1] += qv * k_s[sj0 + 1][d];
            sacc[2] += qv * k_s[sj0 + 2][d];
            sacc[3] += qv * k_s[sj0 + 3][d];
        }
        __syncthreads();
    }

    const float scale = 1.0f / 32.0f;   // 1/sqrt(1024)
    p_s[si][sj0 + 0] = sacc[0] * scale;
    p_s[si][sj0 + 1] = sacc[1] * scale;
    p_s[si][sj0 + 2] = sacc[2] * scale;
    p_s[si][sj0 + 3] = sacc[3] * scale;
    __syncthreads();

    // softmax over j <= i (rows handled by lanes 0..31; tiny)
    if (t < NB) {
        const int i = t;
        float mx = p_s[i][0];
        for (int j = 1; j <= i; ++j) mx = fmaxf(mx, p_s[i][j]);
        float sum = 0.f;
        for (int j = 0; j <= i; ++j) { float e = __expf(p_s[i][j] - mx); p_s[i][j] = e; sum += e; }
        const float inv = 1.0f / sum;
        for (int j = 0; j <= i; ++j) p_s[i][j] *= inv;
        for (int j = i + 1; j < NB; ++j) p_s[i][j] = 0.f;
    }
    __syncthreads();

    // PV: each thread owns 4 consecutive d for 8 rows per pass (4 passes)
    const int d0 = t * 4;               // 256 threads * 4 = 1024
    const float* vbase = base + 2 * DD;
    #pragma unroll 1
    for (int p = 0; p < 4; ++p) {
        float4 acc[8];
        #pragma unroll
        for (int ii = 0; ii < 8; ++ii) acc[ii] = make_float4(0.f, 0.f, 0.f, 0.f);
        const int jmax = (p + 1) * 8;   // causality: rows in this pass have i < jmax
        for (int j = 0; j < jmax; ++j) {
            float4 v4 = *(const float4*)(vbase + (size_t)j * rowstride + d0);
            #pragma unroll
            for (int ii = 0; ii < 8; ++ii) {
                const float pij = p_s[p * 8 + ii][j];   // 0 for j > i
                acc[ii].x += pij * v4.x;
                acc[ii].y += pij * v4.y;
                acc[ii].z += pij * v4.z;
                acc[ii].w += pij * v4.w;
            }
        }
        #pragma unroll
        for (int ii = 0; ii < 8; ++ii) {
            const int i = p * 8 + ii;
            *(float4*)(out + ((size_t)(b * NB + i) * BL + bl) * DD + d0) = acc[ii];
        }
    }
}

extern "C" void kernel_launch(void* const* d_in, const int* in_sizes, int n_in,
                              void* d_out, int out_size, void* d_ws, size_t ws_size,
                              hipStream_t stream) {
    (void)in_sizes; (void)n_in; (void)out_size; (void)ws_size;
    const float* x    = (const float*)d_in[0];
    const float* Wqkv = (const float*)d_in[1];
    const float* bqkv = (const float*)d_in[2];
    const float* Wout = (const float*)d_in[3];
    const float* bout = (const float*)d_in[4];
    float* out = (float*)d_out;

    float* qkv  = (float*)d_ws;                        // 16384 x 3072 fp32 (192 MiB)
    float* attn = qkv + (size_t)SS * BB * 3 * DD / 4 * 4; // placeholder, fixed below

    // proper offsets
    qkv  = (float*)d_ws;
    attn = qkv + (size_t)(BB * SS) * (3 * DD);         // + 64 MiB region

    const int M = BB * SS;                              // 16384

    dim3 blk(256);
    gemm_bias_f32<64, 64, 16><<<dim3((3 * DD) / 64, M / 64), blk, 0, stream>>>(
        x, Wqkv, bqkv, qkv, M, 3 * DD, DD);

    col_attn<<<dim3(BB * BL), blk, 0, stream>>>(qkv, attn);

    gemm_bias_f32<64, 64, 16><<<dim3(DD / 64, M / 64), blk, 0, stream>>>(
        attn, Wout, bout, out, M, DD, DD);
}

// Round 2
// 307.126 us; speedup vs baseline: 6.8426x; 6.8426x over previous
//
#include <hip/hip_runtime.h>
#include <math.h>

#define BB   4
#define SS   4096
#define DD   1024
#define BL   128
#define NB   32

typedef __attribute__((ext_vector_type(4))) float f32x4;
typedef __attribute__((ext_vector_type(8))) short bf16x8;
typedef __attribute__((ext_vector_type(8))) unsigned short u16x8;

__device__ __forceinline__ float bf2f(unsigned short u) {
    return __uint_as_float(((unsigned int)u) << 16);
}
__device__ __forceinline__ unsigned short f2bf(float f) {
    unsigned int u = __float_as_uint(f);
    return (unsigned short)((u + 0x7FFFu + ((u >> 16) & 1u)) >> 16);  // RNE
}

__device__ __forceinline__ void gload_lds16(const unsigned short* g, unsigned short* l) {
    __builtin_amdgcn_global_load_lds(
        (const __attribute__((address_space(1))) void*)g,
        (__attribute__((address_space(3))) void*)l, 16, 0, 0);
}

// ---------------- fp32 -> bf16 elementwise ----------------
__global__ __launch_bounds__(256) void cvt_f32_bf16(const float4* __restrict__ in,
                                                    ushort4* __restrict__ out, int n4) {
    int i = blockIdx.x * 256 + threadIdx.x;
    if (i < n4) {
        float4 v = in[i];
        ushort4 o;
        o.x = f2bf(v.x); o.y = f2bf(v.y); o.z = f2bf(v.z); o.w = f2bf(v.w);
        out[i] = o;
    }
}

// ---------------- transpose + convert: W[K][N] f32 -> WT[N][K] bf16 ----------------
__global__ __launch_bounds__(256) void transcvt(const float* __restrict__ W,
                                                unsigned short* __restrict__ WT,
                                                int K, int N) {
    __shared__ float tile[32][33];
    const int n0 = blockIdx.x * 32, k0 = blockIdx.y * 32;
    const int tx = threadIdx.x & 31, ty = threadIdx.x >> 5;  // ty 0..7
    #pragma unroll
    for (int r = 0; r < 32; r += 8)
        tile[ty + r][tx] = W[(size_t)(k0 + ty + r) * N + n0 + tx];
    __syncthreads();
    #pragma unroll
    for (int r = 0; r < 32; r += 8)
        WT[(size_t)(n0 + ty + r) * K + k0 + tx] = f2bf(tile[tx][ty + r]);
}

// ---------------- bf16 MFMA GEMM (m97 structure): C = A @ BT^T + bias ----------------
// A: [M][K] bf16 row-major; BT: [N][K] bf16 (i.e. B transposed); C: [M][N] OutT.
// 128x128 tile, BK=32, 256 threads = 4 waves (2x2), each wave 64x64 = 4x4 frags.
template<typename OutT>
__global__ __launch_bounds__(256) void gemm_mfma_bf16(
    const unsigned short* __restrict__ A, const unsigned short* __restrict__ BT,
    const float* __restrict__ bias, OutT* __restrict__ C,
    int M, int N, int K, int ntn)
{
    constexpr int BM = 128, BN = 128, BK = 32;
    __shared__ unsigned short As[BM][BK];   // 8 KB
    __shared__ unsigned short Bs[BN][BK];   // 8 KB

    // bijective XCD swizzle (grid % 8 == 0 for all our launches)
    const int nwg = gridDim.x;
    const int wg  = blockIdx.x;
    const int swz = (wg & 7) * (nwg >> 3) + (wg >> 3);
    const int tm = swz / ntn, tn = swz % ntn;
    const int m0 = tm * BM, n0 = tn * BN;

    const int t    = threadIdx.x;
    const int wid  = t >> 6;
    const int lane = t & 63;
    const int wm = wid >> 1, wn = wid & 1;

    // staging: wave wid covers tile rows [wid*32, wid*32+32), two 16-row loads
    const unsigned short* Ag = A + (size_t)(m0 + wid * 32 + (lane >> 2)) * K + (lane & 3) * 8;
    const unsigned short* Bg = BT + (size_t)(n0 + wid * 32 + (lane >> 2)) * K + (lane & 3) * 8;
    unsigned short* lA0 = &As[wid * 32][0];
    unsigned short* lA1 = &As[wid * 32 + 16][0];
    unsigned short* lB0 = &Bs[wid * 32][0];
    unsigned short* lB1 = &Bs[wid * 32 + 16][0];

    // fragment read base: lane l -> row (l&15), k = (l>>4)*8
    const unsigned short* pA = &As[wm * 64 + (lane & 15)][(lane >> 4) * 8];
    const unsigned short* pB = &Bs[wn * 64 + (lane & 15)][(lane >> 4) * 8];

    f32x4 acc[4][4];
    #pragma unroll
    for (int i = 0; i < 4; ++i)
        #pragma unroll
        for (int j = 0; j < 4; ++j) acc[i][j] = (f32x4){0.f, 0.f, 0.f, 0.f};

    for (int k0 = 0; k0 < K; k0 += BK) {
        gload_lds16(Ag + k0, lA0);
        gload_lds16(Ag + (size_t)16 * K + k0, lA1);
        gload_lds16(Bg + k0, lB0);
        gload_lds16(Bg + (size_t)16 * K + k0, lB1);
        __syncthreads();

        bf16x8 a[4], b[4];
        #pragma unroll
        for (int mi = 0; mi < 4; ++mi) a[mi] = *(const bf16x8*)(pA + mi * 16 * BK);
        #pragma unroll
        for (int ni = 0; ni < 4; ++ni) b[ni] = *(const bf16x8*)(pB + ni * 16 * BK);
        #pragma unroll
        for (int mi = 0; mi < 4; ++mi)
            #pragma unroll
            for (int ni = 0; ni < 4; ++ni)
                acc[mi][ni] = __builtin_amdgcn_mfma_f32_16x16x32_bf16(
                    a[mi], b[ni], acc[mi][ni], 0, 0, 0);
        __syncthreads();
    }

    // epilogue: D row = (lane>>4)*4 + r, col = lane&15
    #pragma unroll
    for (int ni = 0; ni < 4; ++ni) {
        const int col = n0 + wn * 64 + ni * 16 + (lane & 15);
        const float bv = bias[col];
        #pragma unroll
        for (int mi = 0; mi < 4; ++mi) {
            const int rbase = m0 + wm * 64 + mi * 16 + (lane >> 4) * 4;
            #pragma unroll
            for (int r = 0; r < 4; ++r) {
                float v = acc[mi][ni][r] + bv;
                if constexpr (sizeof(OutT) == 2)
                    C[(size_t)(rbase + r) * N + col] = f2bf(v);
                else
                    C[(size_t)(rbase + r) * N + col] = v;
            }
        }
    }
}

// ---------------- column attention (bf16 in, bf16 out) ----------------
// One block per (b, bl). L = NB = 32 over block axis, D = 1024, causal.
__global__ __launch_bounds__(256) void col_attn_bf16(const unsigned short* __restrict__ qkv,
                                                     unsigned short* __restrict__ outb)
{
    const int b  = blockIdx.x >> 7;
    const int bl = blockIdx.x & (BL - 1);

    __shared__ float q_s[NB][65];
    __shared__ float k_s[NB][65];
    __shared__ float p_s[NB][NB + 1];

    const int t   = threadIdx.x;
    const int si  = t >> 3;
    const int sj0 = (t & 7) * 4;
    const int lr  = t >> 3;          // stage row 0..31
    const int lc  = (t & 7) * 8;     // stage col group (8 bf16 = 16B)

    const size_t rowstride = (size_t)BL * 3 * DD;
    const unsigned short* base = qkv + ((size_t)b * NB * BL + bl) * (3 * DD);

    float sacc[4] = {0.f, 0.f, 0.f, 0.f};

    for (int d0 = 0; d0 < DD; d0 += 64) {
        u16x8 qv = *(const u16x8*)(base + (size_t)lr * rowstride + d0 + lc);
        u16x8 kv = *(const u16x8*)(base + (size_t)lr * rowstride + DD + d0 + lc);
        #pragma unroll
        for (int j = 0; j < 8; ++j) {
            q_s[lr][lc + j] = bf2f(qv[j]);
            k_s[lr][lc + j] = bf2f(kv[j]);
        }
        __syncthreads();
        #pragma unroll
        for (int d = 0; d < 64; ++d) {
            const float q = q_s[si][d];
            sacc[0] += q * k_s[sj0 + 0][d];
            sacc[1] += q * k_s[sj0 + 1][d];
            sacc[2] += q * k_s[sj0 + 2][d];
            sacc[3] += q * k_s[sj0 + 3][d];
        }
        __syncthreads();
    }

    const float scale = 1.0f / 32.0f;
    p_s[si][sj0 + 0] = sacc[0] * scale;
    p_s[si][sj0 + 1] = sacc[1] * scale;
    p_s[si][sj0 + 2] = sacc[2] * scale;
    p_s[si][sj0 + 3] = sacc[3] * scale;
    __syncthreads();

    if (t < NB) {
        const int i = t;
        float mx = p_s[i][0];
        for (int j = 1; j <= i; ++j) mx = fmaxf(mx, p_s[i][j]);
        float sum = 0.f;
        for (int j = 0; j <= i; ++j) { float e = __expf(p_s[i][j] - mx); p_s[i][j] = e; sum += e; }
        const float inv = 1.0f / sum;
        for (int j = 0; j <= i; ++j) p_s[i][j] *= inv;
        for (int j = i + 1; j < NB; ++j) p_s[i][j] = 0.f;
    }
    __syncthreads();

    const int d0v = t * 4;
    const unsigned short* vbase = base + 2 * DD;
    #pragma unroll 1
    for (int p = 0; p < 4; ++p) {
        float4 acc[8];
        #pragma unroll
        for (int ii = 0; ii < 8; ++ii) acc[ii] = make_float4(0.f, 0.f, 0.f, 0.f);
        const int jmax = (p + 1) * 8;
        for (int j = 0; j < jmax; ++j) {
            ushort4 v4 = *(const ushort4*)(vbase + (size_t)j * rowstride + d0v);
            const float vx = bf2f(v4.x), vy = bf2f(v4.y), vz = bf2f(v4.z), vw = bf2f(v4.w);
            #pragma unroll
            for (int ii = 0; ii < 8; ++ii) {
                const float pij = p_s[p * 8 + ii][j];
                acc[ii].x += pij * vx;
                acc[ii].y += pij * vy;
                acc[ii].z += pij * vz;
                acc[ii].w += pij * vw;
            }
        }
        #pragma unroll
        for (int ii = 0; ii < 8; ++ii) {
            const int i = p * 8 + ii;
            ushort4 o;
            o.x = f2bf(acc[ii].x); o.y = f2bf(acc[ii].y);
            o.z = f2bf(acc[ii].z); o.w = f2bf(acc[ii].w);
            *(ushort4*)(outb + ((size_t)(b * NB + i) * BL + bl) * DD + d0v) = o;
        }
    }
}

extern "C" void kernel_launch(void* const* d_in, const int* in_sizes, int n_in,
                              void* d_out, int out_size, void* d_ws, size_t ws_size,
                              hipStream_t stream) {
    (void)in_sizes; (void)n_in; (void)out_size; (void)ws_size;
    const float* x    = (const float*)d_in[0];
    const float* Wqkv = (const float*)d_in[1];
    const float* bqkv = (const float*)d_in[2];
    const float* Wout = (const float*)d_in[3];
    const float* bout = (const float*)d_in[4];
    float* out = (float*)d_out;

    char* ws = (char*)d_ws;
    unsigned short* xb    = (unsigned short*)ws;                        // 32 MiB
    unsigned short* WqkvT = (unsigned short*)(ws + ((size_t)32 << 20)); //  6 MiB
    unsigned short* WoutT = (unsigned short*)(ws + ((size_t)38 << 20)); //  2 MiB
    unsigned short* qkvb  = (unsigned short*)(ws + ((size_t)40 << 20)); // 96 MiB
    unsigned short* attnb = (unsigned short*)(ws + ((size_t)136 << 20));// 32 MiB

    const int M = BB * SS;  // 16384

    // x -> bf16
    cvt_f32_bf16<<<dim3((M * DD / 4 + 255) / 256), dim3(256), 0, stream>>>(
        (const float4*)x, (ushort4*)xb, M * DD / 4);
    // W -> W^T bf16
    transcvt<<<dim3(3 * DD / 32, DD / 32), dim3(256), 0, stream>>>(Wqkv, WqkvT, DD, 3 * DD);
    transcvt<<<dim3(DD / 32, DD / 32), dim3(256), 0, stream>>>(Wout, WoutT, DD, DD);

    // QKV = x @ Wqkv + bqkv  (bf16 out)
    gemm_mfma_bf16<unsigned short><<<dim3((M / 128) * (3 * DD / 128)), dim3(256), 0, stream>>>(
        xb, WqkvT, bqkv, qkvb, M, 3 * DD, DD, 3 * DD / 128);

    // column attention (bf16 -> bf16)
    col_attn_bf16<<<dim3(BB * BL), dim3(256), 0, stream>>>(qkvb, attnb);

    // out = attn @ Wout + bout  (fp32 out)
    gemm_mfma_bf16<float><<<dim3((M / 128) * (DD / 128)), dim3(256), 0, stream>>>(
        attnb, WoutT, bout, out, M, DD, DD, DD / 128);
}

// Round 3
// 258.180 us; speedup vs baseline: 8.1398x; 1.1896x over previous
//
#include <hip/hip_runtime.h>
#include <math.h>

#define BB   4
#define SS   4096
#define DD   1024
#define BL   128
#define NB   32

typedef __attribute__((ext_vector_type(4))) float f32x4;
typedef __attribute__((ext_vector_type(8))) short bf16x8;
typedef __attribute__((ext_vector_type(8))) unsigned short u16x8;

__device__ __forceinline__ float bf2f(unsigned short u) {
    return __uint_as_float(((unsigned int)u) << 16);
}
__device__ __forceinline__ unsigned short f2bf(float f) {
    unsigned int u = __float_as_uint(f);
    return (unsigned short)((u + 0x7FFFu + ((u >> 16) & 1u)) >> 16);  // RNE
}
__device__ __forceinline__ void gload_lds16(const unsigned short* g, unsigned short* l) {
    __builtin_amdgcn_global_load_lds(
        (const __attribute__((address_space(1))) void*)g,
        (__attribute__((address_space(3))) void*)l, 16, 0, 0);
}

// ---------------- fp32 -> bf16 elementwise ----------------
__global__ __launch_bounds__(256) void cvt_f32_bf16(const float4* __restrict__ in,
                                                    ushort4* __restrict__ out, int n4) {
    int i = blockIdx.x * 256 + threadIdx.x;
    if (i < n4) {
        float4 v = in[i];
        ushort4 o;
        o.x = f2bf(v.x); o.y = f2bf(v.y); o.z = f2bf(v.z); o.w = f2bf(v.w);
        out[i] = o;
    }
}

// ---------------- transpose + convert: W[K][N] f32 -> WT[N][K] bf16 ----------------
__global__ __launch_bounds__(256) void transcvt(const float* __restrict__ W,
                                                unsigned short* __restrict__ WT,
                                                int K, int N) {
    __shared__ float tile[32][33];
    const int n0 = blockIdx.x * 32, k0 = blockIdx.y * 32;
    const int tx = threadIdx.x & 31, ty = threadIdx.x >> 5;  // ty 0..7
    #pragma unroll
    for (int r = 0; r < 32; r += 8)
        tile[ty + r][tx] = W[(size_t)(k0 + ty + r) * N + n0 + tx];
    __syncthreads();
    #pragma unroll
    for (int r = 0; r < 32; r += 8)
        WT[(size_t)(n0 + ty + r) * K + k0 + tx] = f2bf(tile[tx][ty + r]);
}

// ---------------- 256x256 8-phase bf16 MFMA GEMM: C = A @ BT^T + bias ----------------
// A: [M][K] bf16 row-major; BT: [N][K] bf16; C: [M][N] OutT.
// BK=64, 512 threads = 8 waves (2M x 4N). Per wave: 128x64 out = 8 M-frags x 4 N-frags.
// LDS: 2 dbuf x (256x64) A + B, XOR-swizzled in 16B chunks: phys = logical ^ (row&7).
// B register-resident per K-tile; A read per phase (4 quadrants of 2 M-frags).
// Counted vmcnt(6) at tile boundary only (3 half-tiles in flight).

#define GBAR() __builtin_amdgcn_s_barrier()
#define LGKM0() do { asm volatile("s_waitcnt lgkmcnt(0)" ::: "memory"); \
                     __builtin_amdgcn_sched_barrier(0); } while (0)

#define MFMA_PAIR(q, ni) \
    acc[(q)*2+0][ni] = __builtin_amdgcn_mfma_f32_16x16x32_bf16(a[0][0], breg[ni][0], acc[(q)*2+0][ni], 0, 0, 0); \
    acc[(q)*2+0][ni] = __builtin_amdgcn_mfma_f32_16x16x32_bf16(a[0][1], breg[ni][1], acc[(q)*2+0][ni], 0, 0, 0); \
    acc[(q)*2+1][ni] = __builtin_amdgcn_mfma_f32_16x16x32_bf16(a[1][0], breg[ni][0], acc[(q)*2+1][ni], 0, 0, 0); \
    acc[(q)*2+1][ni] = __builtin_amdgcn_mfma_f32_16x16x32_bf16(a[1][1], breg[ni][1], acc[(q)*2+1][ni], 0, 0, 0);

#define MFMA_Q(q) do { \
    __builtin_amdgcn_s_setprio(1); \
    MFMA_PAIR(q, 0) MFMA_PAIR(q, 1) MFMA_PAIR(q, 2) MFMA_PAIR(q, 3) \
    __builtin_amdgcn_s_setprio(0); } while (0)

#define LOAD_A(q) do { \
    a[0][0] = *(const bf16x8*)(pA + ((q)*2+0)*1024 + sw0); \
    a[0][1] = *(const bf16x8*)(pA + ((q)*2+0)*1024 + sw1); \
    a[1][0] = *(const bf16x8*)(pA + ((q)*2+1)*1024 + sw0); \
    a[1][1] = *(const bf16x8*)(pA + ((q)*2+1)*1024 + sw1); } while (0)

template<typename OutT>
__global__ __launch_bounds__(512, 2) void gemm256(
    const unsigned short* __restrict__ A, const unsigned short* __restrict__ BT,
    const float* __restrict__ bias, OutT* __restrict__ C,
    int M, int N, int K, int ntn)
{
    __shared__ unsigned short sA[2][256][64];   // 64 KiB
    __shared__ unsigned short sB[2][256][64];   // 64 KiB

    const int nwg = gridDim.x;
    const int wg  = blockIdx.x;
    const int swzb = (wg & 7) * (nwg >> 3) + (wg >> 3);   // bijective: nwg % 8 == 0
    const int m0 = (swzb / ntn) * 256, n0 = (swzb % ntn) * 256;

    const int t    = threadIdx.x;
    const int w    = t >> 6;
    const int lane = t & 63;
    const int wm   = w >> 2, wn = w & 3;

    // staging constants: per 64-row chunk, lane covers row (w*8 + lane>>3), slot lane&7
    const int srow8 = lane >> 3;
    const int sgch  = (lane & 7) ^ srow8;     // pre-swizzled global k-chunk
    const int NT    = K >> 6;                 // K-tiles of 64

    auto STAGE_A = [&](int ts, int cb) {
        const int r = cb + (w << 3);
        gload_lds16(A + (size_t)(m0 + r + srow8) * K + (ts << 6) + sgch * 8,
                    &sA[ts & 1][r][0]);
    };
    auto STAGE_B = [&](int ts, int cb) {
        const int r = cb + (w << 3);
        gload_lds16(BT + (size_t)(n0 + r + srow8) * K + (ts << 6) + sgch * 8,
                    &sB[ts & 1][r][0]);
    };

    // fragment read bases: row = frag_row_base + (lane&15); chunk = (lane>>4) + kk*4,
    // phys chunk = chunk ^ (row&7) = chunk ^ (lane&7)
    const int frA = wm * 128 + (lane & 15);
    const int frB = wn * 64  + (lane & 15);
    const int sw0 = (((lane >> 4) + 0) ^ (lane & 7)) * 8;
    const int sw1 = (((lane >> 4) + 4) ^ (lane & 7)) * 8;

    f32x4 acc[8][4];
    #pragma unroll
    for (int i = 0; i < 8; ++i)
        #pragma unroll
        for (int j = 0; j < 4; ++j) acc[i][j] = (f32x4){0.f, 0.f, 0.f, 0.f};

    // ---- prologue: tile 0 fully; tile 1's B + A-lo (6 insts stay in flight) ----
    STAGE_B(0, 0); STAGE_B(0, 64); STAGE_B(0, 128); STAGE_B(0, 192);
    STAGE_A(0, 0); STAGE_A(0, 64); STAGE_A(0, 128); STAGE_A(0, 192);
    asm volatile("s_waitcnt vmcnt(4)" ::: "memory");
    if (NT > 1) {
        STAGE_B(1, 0); STAGE_B(1, 64); STAGE_B(1, 128); STAGE_B(1, 192);
        STAGE_A(1, 0); STAGE_A(1, 128);
        asm volatile("s_waitcnt vmcnt(6)" ::: "memory");
    } else {
        asm volatile("s_waitcnt vmcnt(0)" ::: "memory");
    }
    GBAR();

    for (int ts = 0; ts < NT; ++ts) {
        const unsigned short* pA = &sA[ts & 1][frA][0];
        const unsigned short* pB = &sB[ts & 1][frB][0];
        bf16x8 breg[4][2];
        bf16x8 a[2][2];

        // ---- phase 1: B->regs + A-q0; stage A-hi(ts+1) ----
        #pragma unroll
        for (int ni = 0; ni < 4; ++ni) {
            breg[ni][0] = *(const bf16x8*)(pB + ni * 1024 + sw0);
            breg[ni][1] = *(const bf16x8*)(pB + ni * 1024 + sw1);
        }
        LOAD_A(0);
        if (ts + 1 < NT) { STAGE_A(ts + 1, 64); STAGE_A(ts + 1, 192); }
        GBAR(); LGKM0(); MFMA_Q(0); GBAR();

        // ---- phase 2: A-q1; stage B-lo(ts+2) ----
        LOAD_A(1);
        if (ts + 2 < NT) { STAGE_B(ts + 2, 0); STAGE_B(ts + 2, 64); }
        GBAR(); LGKM0(); MFMA_Q(1); GBAR();

        // ---- phase 3: A-q2; stage B-hi(ts+2) ----
        LOAD_A(2);
        if (ts + 2 < NT) { STAGE_B(ts + 2, 128); STAGE_B(ts + 2, 192); }
        GBAR(); LGKM0(); MFMA_Q(2); GBAR();

        // ---- phase 4: A-q3; stage A-lo(ts+2); counted vmcnt ----
        LOAD_A(3);
        if (ts + 2 < NT) { STAGE_A(ts + 2, 0); STAGE_A(ts + 2, 128); }
        GBAR(); LGKM0(); MFMA_Q(3);
        if (ts + 2 < NT) asm volatile("s_waitcnt vmcnt(6)" ::: "memory");
        else             asm volatile("s_waitcnt vmcnt(0)" ::: "memory");
        GBAR();
    }

    // ---- epilogue ----
    #pragma unroll
    for (int ni = 0; ni < 4; ++ni) {
        const int col = n0 + wn * 64 + ni * 16 + (lane & 15);
        const float bv = bias[col];
        #pragma unroll
        for (int mi = 0; mi < 8; ++mi) {
            const int rb = m0 + wm * 128 + mi * 16 + ((lane >> 4) << 2);
            #pragma unroll
            for (int r = 0; r < 4; ++r) {
                float v = acc[mi][ni][r] + bv;
                if constexpr (sizeof(OutT) == 2)
                    C[(size_t)(rb + r) * N + col] = f2bf(v);
                else
                    C[(size_t)(rb + r) * N + col] = v;
            }
        }
    }
}

// ---------------- column attention (bf16 in, bf16 out) ----------------
__global__ __launch_bounds__(256) void col_attn_bf16(const unsigned short* __restrict__ qkv,
                                                     unsigned short* __restrict__ outb)
{
    const int b  = blockIdx.x >> 7;
    const int bl = blockIdx.x & (BL - 1);

    __shared__ float q_s[NB][65];
    __shared__ float k_s[NB][65];
    __shared__ float p_s[NB][NB + 1];

    const int t   = threadIdx.x;
    const int si  = t >> 3;
    const int sj0 = (t & 7) * 4;
    const int lr  = t >> 3;
    const int lc  = (t & 7) * 8;

    const size_t rowstride = (size_t)BL * 3 * DD;
    const unsigned short* base = qkv + ((size_t)b * NB * BL + bl) * (3 * DD);

    float sacc[4] = {0.f, 0.f, 0.f, 0.f};

    for (int d0 = 0; d0 < DD; d0 += 64) {
        u16x8 qv = *(const u16x8*)(base + (size_t)lr * rowstride + d0 + lc);
        u16x8 kv = *(const u16x8*)(base + (size_t)lr * rowstride + DD + d0 + lc);
        #pragma unroll
        for (int j = 0; j < 8; ++j) {
            q_s[lr][lc + j] = bf2f(qv[j]);
            k_s[lr][lc + j] = bf2f(kv[j]);
        }
        __syncthreads();
        #pragma unroll
        for (int d = 0; d < 64; ++d) {
            const float q = q_s[si][d];
            sacc[0] += q * k_s[sj0 + 0][d];
            sacc[1] += q * k_s[sj0 + 1][d];
            sacc[2] += q * k_s[sj0 + 2][d];
            sacc[3] += q * k_s[sj0 + 3][d];
        }
        __syncthreads();
    }

    const float scale = 1.0f / 32.0f;
    p_s[si][sj0 + 0] = sacc[0] * scale;
    p_s[si][sj0 + 1] = sacc[1] * scale;
    p_s[si][sj0 + 2] = sacc[2] * scale;
    p_s[si][sj0 + 3] = sacc[3] * scale;
    __syncthreads();

    if (t < NB) {
        const int i = t;
        float mx = p_s[i][0];
        for (int j = 1; j <= i; ++j) mx = fmaxf(mx, p_s[i][j]);
        float sum = 0.f;
        for (int j = 0; j <= i; ++j) { float e = __expf(p_s[i][j] - mx); p_s[i][j] = e; sum += e; }
        const float inv = 1.0f / sum;
        for (int j = 0; j <= i; ++j) p_s[i][j] *= inv;
        for (int j = i + 1; j < NB; ++j) p_s[i][j] = 0.f;
    }
    __syncthreads();

    const int d0v = t * 4;
    const unsigned short* vbase = base + 2 * DD;
    #pragma unroll 1
    for (int p = 0; p < 4; ++p) {
        float4 acc[8];
        #pragma unroll
        for (int ii = 0; ii < 8; ++ii) acc[ii] = make_float4(0.f, 0.f, 0.f, 0.f);
        const int jmax = (p + 1) * 8;
        for (int j = 0; j < jmax; ++j) {
            ushort4 v4 = *(const ushort4*)(vbase + (size_t)j * rowstride + d0v);
            const float vx = bf2f(v4.x), vy = bf2f(v4.y), vz = bf2f(v4.z), vw = bf2f(v4.w);
            #pragma unroll
            for (int ii = 0; ii < 8; ++ii) {
                const float pij = p_s[p * 8 + ii][j];
                acc[ii].x += pij * vx;
                acc[ii].y += pij * vy;
                acc[ii].z += pij * vz;
                acc[ii].w += pij * vw;
            }
        }
        #pragma unroll
        for (int ii = 0; ii < 8; ++ii) {
            const int i = p * 8 + ii;
            ushort4 o;
            o.x = f2bf(acc[ii].x); o.y = f2bf(acc[ii].y);
            o.z = f2bf(acc[ii].z); o.w = f2bf(acc[ii].w);
            *(ushort4*)(outb + ((size_t)(b * NB + i) * BL + bl) * DD + d0v) = o;
        }
    }
}

extern "C" void kernel_launch(void* const* d_in, const int* in_sizes, int n_in,
                              void* d_out, int out_size, void* d_ws, size_t ws_size,
                              hipStream_t stream) {
    (void)in_sizes; (void)n_in; (void)out_size; (void)ws_size;
    const float* x    = (const float*)d_in[0];
    const float* Wqkv = (const float*)d_in[1];
    const float* bqkv = (const float*)d_in[2];
    const float* Wout = (const float*)d_in[3];
    const float* bout = (const float*)d_in[4];
    float* out = (float*)d_out;

    char* ws = (char*)d_ws;
    unsigned short* xb    = (unsigned short*)ws;                        // 32 MiB
    unsigned short* WqkvT = (unsigned short*)(ws + ((size_t)32 << 20)); //  6 MiB
    unsigned short* WoutT = (unsigned short*)(ws + ((size_t)38 << 20)); //  2 MiB
    unsigned short* qkvb  = (unsigned short*)(ws + ((size_t)40 << 20)); // 96 MiB
    unsigned short* attnb = (unsigned short*)(ws + ((size_t)136 << 20));// 32 MiB

    const int M = BB * SS;  // 16384

    cvt_f32_bf16<<<dim3((M * DD / 4 + 255) / 256), dim3(256), 0, stream>>>(
        (const float4*)x, (ushort4*)xb, M * DD / 4);
    transcvt<<<dim3(3 * DD / 32, DD / 32), dim3(256), 0, stream>>>(Wqkv, WqkvT, DD, 3 * DD);
    transcvt<<<dim3(DD / 32, DD / 32), dim3(256), 0, stream>>>(Wout, WoutT, DD, DD);

    // QKV = x @ Wqkv + bqkv  (bf16 out): grid 64 x 12 = 768 tiles
    gemm256<unsigned short><<<dim3((M / 256) * (3 * DD / 256)), dim3(512), 0, stream>>>(
        xb, WqkvT, bqkv, qkvb, M, 3 * DD, DD, 3 * DD / 256);

    col_attn_bf16<<<dim3(BB * BL), dim3(256), 0, stream>>>(qkvb, attnb);

    // out = attn @ Wout + bout  (fp32 out): grid 64 x 4 = 256 tiles
    gemm256<float><<<dim3((M / 256) * (DD / 256)), dim3(512), 0, stream>>>(
        attnb, WoutT, bout, out, M, DD, DD, DD / 256);
}

// Round 4
// 249.893 us; speedup vs baseline: 8.4098x; 1.0332x over previous
//
#include <hip/hip_runtime.h>
#include <math.h>

#define BB   4
#define SS   4096
#define DD   1024
#define BL   128
#define NB   32

typedef __attribute__((ext_vector_type(4))) float f32x4;
typedef __attribute__((ext_vector_type(8))) short bf16x8;
typedef __attribute__((ext_vector_type(8))) unsigned short u16x8;

__device__ __forceinline__ float bf2f(unsigned short u) {
    return __uint_as_float(((unsigned int)u) << 16);
}
__device__ __forceinline__ unsigned short f2bf(float f) {
    unsigned int u = __float_as_uint(f);
    return (unsigned short)((u + 0x7FFFu + ((u >> 16) & 1u)) >> 16);  // RNE
}
__device__ __forceinline__ void gload_lds16(const unsigned short* g, unsigned short* l) {
    __builtin_amdgcn_global_load_lds(
        (const __attribute__((address_space(1))) void*)g,
        (__attribute__((address_space(3))) void*)l, 16, 0, 0);
}

// ---------------- fp32 -> bf16 elementwise ----------------
__global__ __launch_bounds__(256) void cvt_f32_bf16(const float4* __restrict__ in,
                                                    ushort4* __restrict__ out, int n4) {
    int i = blockIdx.x * 256 + threadIdx.x;
    if (i < n4) {
        float4 v = in[i];
        ushort4 o;
        o.x = f2bf(v.x); o.y = f2bf(v.y); o.z = f2bf(v.z); o.w = f2bf(v.w);
        out[i] = o;
    }
}

// ---------------- transpose + convert: W[K][N] f32 -> WT[N][K] bf16 ----------------
__global__ __launch_bounds__(256) void transcvt(const float* __restrict__ W,
                                                unsigned short* __restrict__ WT,
                                                int K, int N) {
    __shared__ float tile[32][33];
    const int n0 = blockIdx.x * 32, k0 = blockIdx.y * 32;
    const int tx = threadIdx.x & 31, ty = threadIdx.x >> 5;  // ty 0..7
    #pragma unroll
    for (int r = 0; r < 32; r += 8)
        tile[ty + r][tx] = W[(size_t)(k0 + ty + r) * N + n0 + tx];
    __syncthreads();
    #pragma unroll
    for (int r = 0; r < 32; r += 8)
        WT[(size_t)(n0 + ty + r) * K + k0 + tx] = f2bf(tile[tx][ty + r]);
}

// ---------------- 256x256 8-phase bf16 MFMA GEMM: C = A @ BT^T + bias ----------------
// A: [M][K] bf16 row-major; BT: [N][K] bf16; C: [M][N] OutT.
// BK=64, 512 threads = 8 waves (2M x 4N). Per wave: 128x64 out = 8 M-frags x 4 N-frags.
// LDS: 2 dbuf x (256x64) A + B in one 128 KiB arena, XOR-swizzled in 16B chunks.
// Epilogue: LDS-bounce -> fully coalesced wide stores (arena reused as C tile).

#define GBAR() __builtin_amdgcn_s_barrier()
#define LGKM0() do { asm volatile("s_waitcnt lgkmcnt(0)" ::: "memory"); \
                     __builtin_amdgcn_sched_barrier(0); } while (0)

#define MFMA_PAIR(q, ni) \
    acc[(q)*2+0][ni] = __builtin_amdgcn_mfma_f32_16x16x32_bf16(a[0][0], breg[ni][0], acc[(q)*2+0][ni], 0, 0, 0); \
    acc[(q)*2+0][ni] = __builtin_amdgcn_mfma_f32_16x16x32_bf16(a[0][1], breg[ni][1], acc[(q)*2+0][ni], 0, 0, 0); \
    acc[(q)*2+1][ni] = __builtin_amdgcn_mfma_f32_16x16x32_bf16(a[1][0], breg[ni][0], acc[(q)*2+1][ni], 0, 0, 0); \
    acc[(q)*2+1][ni] = __builtin_amdgcn_mfma_f32_16x16x32_bf16(a[1][1], breg[ni][1], acc[(q)*2+1][ni], 0, 0, 0);

#define MFMA_Q(q) do { \
    __builtin_amdgcn_s_setprio(1); \
    MFMA_PAIR(q, 0) MFMA_PAIR(q, 1) MFMA_PAIR(q, 2) MFMA_PAIR(q, 3) \
    __builtin_amdgcn_s_setprio(0); } while (0)

#define LOAD_A(q) do { \
    a[0][0] = *(const bf16x8*)(pA + ((q)*2+0)*1024 + sw0); \
    a[0][1] = *(const bf16x8*)(pA + ((q)*2+0)*1024 + sw1); \
    a[1][0] = *(const bf16x8*)(pA + ((q)*2+1)*1024 + sw0); \
    a[1][1] = *(const bf16x8*)(pA + ((q)*2+1)*1024 + sw1); } while (0)

template<typename OutT>
__global__ __launch_bounds__(512, 2) void gemm256(
    const unsigned short* __restrict__ A, const unsigned short* __restrict__ BT,
    const float* __restrict__ bias, OutT* __restrict__ C,
    int M, int N, int K, int ntn)
{
    __shared__ __align__(16) unsigned short smem[65536];   // 128 KiB arena
    // staging views: sA = smem[0..32767] ([2][256][64]), sB = smem[32768..]
    unsigned short* sAb = smem;
    unsigned short* sBb = smem + 32768;

    const int nwg = gridDim.x;
    const int wg  = blockIdx.x;
    const int swzb = (wg & 7) * (nwg >> 3) + (wg >> 3);   // bijective: nwg % 8 == 0
    const int m0 = (swzb / ntn) * 256, n0 = (swzb % ntn) * 256;

    const int t    = threadIdx.x;
    const int w    = t >> 6;
    const int lane = t & 63;
    const int wm   = w >> 2, wn = w & 3;

    const int srow8 = lane >> 3;
    const int sgch  = (lane & 7) ^ srow8;     // pre-swizzled global k-chunk
    const int NT    = K >> 6;                 // K-tiles of 64

    auto STAGE_A = [&](int ts, int cb) {
        const int r = cb + (w << 3);
        gload_lds16(A + (size_t)(m0 + r + srow8) * K + (ts << 6) + sgch * 8,
                    sAb + (size_t)(ts & 1) * 16384 + r * 64);
    };
    auto STAGE_B = [&](int ts, int cb) {
        const int r = cb + (w << 3);
        gload_lds16(BT + (size_t)(n0 + r + srow8) * K + (ts << 6) + sgch * 8,
                    sBb + (size_t)(ts & 1) * 16384 + r * 64);
    };

    const int frA = wm * 128 + (lane & 15);
    const int frB = wn * 64  + (lane & 15);
    const int sw0 = (((lane >> 4) + 0) ^ (lane & 7)) * 8;
    const int sw1 = (((lane >> 4) + 4) ^ (lane & 7)) * 8;

    f32x4 acc[8][4];
    #pragma unroll
    for (int i = 0; i < 8; ++i)
        #pragma unroll
        for (int j = 0; j < 4; ++j) acc[i][j] = (f32x4){0.f, 0.f, 0.f, 0.f};

    // ---- prologue ----
    STAGE_B(0, 0); STAGE_B(0, 64); STAGE_B(0, 128); STAGE_B(0, 192);
    STAGE_A(0, 0); STAGE_A(0, 64); STAGE_A(0, 128); STAGE_A(0, 192);
    asm volatile("s_waitcnt vmcnt(4)" ::: "memory");
    if (NT > 1) {
        STAGE_B(1, 0); STAGE_B(1, 64); STAGE_B(1, 128); STAGE_B(1, 192);
        STAGE_A(1, 0); STAGE_A(1, 128);
        asm volatile("s_waitcnt vmcnt(6)" ::: "memory");
    } else {
        asm volatile("s_waitcnt vmcnt(0)" ::: "memory");
    }
    GBAR();

    for (int ts = 0; ts < NT; ++ts) {
        const unsigned short* pA = sAb + (size_t)(ts & 1) * 16384 + frA * 64;
        const unsigned short* pB = sBb + (size_t)(ts & 1) * 16384 + frB * 64;
        bf16x8 breg[4][2];
        bf16x8 a[2][2];

        // ---- phase 1: B->regs + A-q0; stage A-hi(ts+1) ----
        #pragma unroll
        for (int ni = 0; ni < 4; ++ni) {
            breg[ni][0] = *(const bf16x8*)(pB + ni * 1024 + sw0);
            breg[ni][1] = *(const bf16x8*)(pB + ni * 1024 + sw1);
        }
        LOAD_A(0);
        if (ts + 1 < NT) { STAGE_A(ts + 1, 64); STAGE_A(ts + 1, 192); }
        GBAR(); LGKM0(); MFMA_Q(0); GBAR();

        // ---- phase 2: A-q1; stage B-lo(ts+2) ----
        LOAD_A(1);
        if (ts + 2 < NT) { STAGE_B(ts + 2, 0); STAGE_B(ts + 2, 64); }
        GBAR(); LGKM0(); MFMA_Q(1); GBAR();

        // ---- phase 3: A-q2; stage B-hi(ts+2) ----
        LOAD_A(2);
        if (ts + 2 < NT) { STAGE_B(ts + 2, 128); STAGE_B(ts + 2, 192); }
        GBAR(); LGKM0(); MFMA_Q(2); GBAR();

        // ---- phase 4: A-q3; stage A-lo(ts+2); counted vmcnt ----
        LOAD_A(3);
        if (ts + 2 < NT) { STAGE_A(ts + 2, 0); STAGE_A(ts + 2, 128); }
        GBAR(); LGKM0(); MFMA_Q(3);
        if (ts + 2 < NT) asm volatile("s_waitcnt vmcnt(6)" ::: "memory");
        else             asm volatile("s_waitcnt vmcnt(0)" ::: "memory");
        GBAR();
    }

    // ---- epilogue: LDS-bounce for coalesced wide stores ----
    if constexpr (sizeof(OutT) == 2) {
        // full 256x256 bf16 C tile = 128 KiB, exactly the arena
        unsigned short (*cb)[256] = (unsigned short (*)[256])smem;
        #pragma unroll
        for (int ni = 0; ni < 4; ++ni) {
            const int col = wn * 64 + ni * 16 + (lane & 15);
            const float bv = bias[n0 + col];
            #pragma unroll
            for (int mi = 0; mi < 8; ++mi) {
                const int rb = wm * 128 + mi * 16 + ((lane >> 4) << 2);
                #pragma unroll
                for (int r = 0; r < 4; ++r)
                    cb[rb + r][col] = f2bf(acc[mi][ni][r] + bv);
            }
        }
        __syncthreads();
        unsigned short* Cp = (unsigned short*)C;
        #pragma unroll
        for (int it = 0; it < 16; ++it) {
            const int row = it * 16 + (t >> 5);
            const int cs  = (t & 31) * 8;
            u16x8 v = *(const u16x8*)&cb[row][cs];
            *(u16x8*)(Cp + (size_t)(m0 + row) * N + n0 + cs) = v;
        }
    } else {
        // f32: two 128-row passes (128 rows x 256 f32 = 128 KiB)
        float (*cf)[256] = (float (*)[256])smem;
        #pragma unroll
        for (int h = 0; h < 2; ++h) {
            if (wm == h) {
                #pragma unroll
                for (int ni = 0; ni < 4; ++ni) {
                    const int col = wn * 64 + ni * 16 + (lane & 15);
                    const float bv = bias[n0 + col];
                    #pragma unroll
                    for (int mi = 0; mi < 8; ++mi) {
                        const int rb = mi * 16 + ((lane >> 4) << 2);  // 0..127
                        #pragma unroll
                        for (int r = 0; r < 4; ++r)
                            cf[rb + r][col] = acc[mi][ni][r] + bv;
                    }
                }
            }
            __syncthreads();
            float* Cp = (float*)C;
            #pragma unroll
            for (int it = 0; it < 16; ++it) {
                const int row = it * 8 + (t >> 6);     // 0..127
                const int c4  = (t & 63) * 4;
                float4 v = *(const float4*)&cf[row][c4];
                *(float4*)(Cp + (size_t)(m0 + h * 128 + row) * N + n0 + c4) = v;
            }
            __syncthreads();
        }
    }
}

// ---------------- column attention (bf16 in, bf16 out) ----------------
__global__ __launch_bounds__(256) void col_attn_bf16(const unsigned short* __restrict__ qkv,
                                                     unsigned short* __restrict__ outb)
{
    const int b  = blockIdx.x >> 7;
    const int bl = blockIdx.x & (BL - 1);

    __shared__ float q_s[NB][65];
    __shared__ float k_s[NB][65];
    __shared__ float p_s[NB][NB + 1];

    const int t   = threadIdx.x;
    const int si  = t >> 3;
    const int sj0 = (t & 7) * 4;
    const int lr  = t >> 3;
    const int lc  = (t & 7) * 8;

    const size_t rowstride = (size_t)BL * 3 * DD;
    const unsigned short* base = qkv + ((size_t)b * NB * BL + bl) * (3 * DD);

    float sacc[4] = {0.f, 0.f, 0.f, 0.f};

    for (int d0 = 0; d0 < DD; d0 += 64) {
        u16x8 qv = *(const u16x8*)(base + (size_t)lr * rowstride + d0 + lc);
        u16x8 kv = *(const u16x8*)(base + (size_t)lr * rowstride + DD + d0 + lc);
        #pragma unroll
        for (int j = 0; j < 8; ++j) {
            q_s[lr][lc + j] = bf2f(qv[j]);
            k_s[lr][lc + j] = bf2f(kv[j]);
        }
        __syncthreads();
        #pragma unroll
        for (int d = 0; d < 64; ++d) {
            const float q = q_s[si][d];
            sacc[0] += q * k_s[sj0 + 0][d];
            sacc[1] += q * k_s[sj0 + 1][d];
            sacc[2] += q * k_s[sj0 + 2][d];
            sacc[3] += q * k_s[sj0 + 3][d];
        }
        __syncthreads();
    }

    const float scale = 1.0f / 32.0f;
    p_s[si][sj0 + 0] = sacc[0] * scale;
    p_s[si][sj0 + 1] = sacc[1] * scale;
    p_s[si][sj0 + 2] = sacc[2] * scale;
    p_s[si][sj0 + 3] = sacc[3] * scale;
    __syncthreads();

    if (t < NB) {
        const int i = t;
        float mx = p_s[i][0];
        for (int j = 1; j <= i; ++j) mx = fmaxf(mx, p_s[i][j]);
        float sum = 0.f;
        for (int j = 0; j <= i; ++j) { float e = __expf(p_s[i][j] - mx); p_s[i][j] = e; sum += e; }
        const float inv = 1.0f / sum;
        for (int j = 0; j <= i; ++j) p_s[i][j] *= inv;
        for (int j = i + 1; j < NB; ++j) p_s[i][j] = 0.f;
    }
    __syncthreads();

    const int d0v = t * 4;
    const unsigned short* vbase = base + 2 * DD;
    #pragma unroll 1
    for (int p = 0; p < 4; ++p) {
        float4 acc[8];
        #pragma unroll
        for (int ii = 0; ii < 8; ++ii) acc[ii] = make_float4(0.f, 0.f, 0.f, 0.f);
        const int jmax = (p + 1) * 8;
        for (int j = 0; j < jmax; ++j) {
            ushort4 v4 = *(const ushort4*)(vbase + (size_t)j * rowstride + d0v);
            const float vx = bf2f(v4.x), vy = bf2f(v4.y), vz = bf2f(v4.z), vw = bf2f(v4.w);
            #pragma unroll
            for (int ii = 0; ii < 8; ++ii) {
                const float pij = p_s[p * 8 + ii][j];
                acc[ii].x += pij * vx;
                acc[ii].y += pij * vy;
                acc[ii].z += pij * vz;
                acc[ii].w += pij * vw;
            }
        }
        #pragma unroll
        for (int ii = 0; ii < 8; ++ii) {
            const int i = p * 8 + ii;
            ushort4 o;
            o.x = f2bf(acc[ii].x); o.y = f2bf(acc[ii].y);
            o.z = f2bf(acc[ii].z); o.w = f2bf(acc[ii].w);
            *(ushort4*)(outb + ((size_t)(b * NB + i) * BL + bl) * DD + d0v) = o;
        }
    }
}

extern "C" void kernel_launch(void* const* d_in, const int* in_sizes, int n_in,
                              void* d_out, int out_size, void* d_ws, size_t ws_size,
                              hipStream_t stream) {
    (void)in_sizes; (void)n_in; (void)out_size; (void)ws_size;
    const float* x    = (const float*)d_in[0];
    const float* Wqkv = (const float*)d_in[1];
    const float* bqkv = (const float*)d_in[2];
    const float* Wout = (const float*)d_in[3];
    const float* bout = (const float*)d_in[4];
    float* out = (float*)d_out;

    char* ws = (char*)d_ws;
    unsigned short* xb    = (unsigned short*)ws;                        // 32 MiB
    unsigned short* WqkvT = (unsigned short*)(ws + ((size_t)32 << 20)); //  6 MiB
    unsigned short* WoutT = (unsigned short*)(ws + ((size_t)38 << 20)); //  2 MiB
    unsigned short* qkvb  = (unsigned short*)(ws + ((size_t)40 << 20)); // 96 MiB
    unsigned short* attnb = (unsigned short*)(ws + ((size_t)136 << 20));// 32 MiB

    const int M = BB * SS;  // 16384

    cvt_f32_bf16<<<dim3((M * DD / 4 + 255) / 256), dim3(256), 0, stream>>>(
        (const float4*)x, (ushort4*)xb, M * DD / 4);
    transcvt<<<dim3(3 * DD / 32, DD / 32), dim3(256), 0, stream>>>(Wqkv, WqkvT, DD, 3 * DD);
    transcvt<<<dim3(DD / 32, DD / 32), dim3(256), 0, stream>>>(Wout, WoutT, DD, DD);

    // QKV = x @ Wqkv + bqkv  (bf16 out): grid 64 x 12 = 768 tiles
    gemm256<unsigned short><<<dim3((M / 256) * (3 * DD / 256)), dim3(512), 0, stream>>>(
        xb, WqkvT, bqkv, qkvb, M, 3 * DD, DD, 3 * DD / 256);

    col_attn_bf16<<<dim3(BB * BL), dim3(256), 0, stream>>>(qkvb, attnb);

    // out = attn @ Wout + bout  (fp32 out): grid 64 x 4 = 256 tiles
    gemm256<float><<<dim3((M / 256) * (DD / 256)), dim3(512), 0, stream>>>(
        attnb, WoutT, bout, out, M, DD, DD, DD / 256);
}

// Round 5
// 216.529 us; speedup vs baseline: 9.7056x; 1.1541x over previous
//
#include <hip/hip_runtime.h>
#include <math.h>

#define BB   4
#define SS   4096
#define DD   1024
#define BL   128
#define NB   32

typedef __attribute__((ext_vector_type(4))) float f32x4;
typedef __attribute__((ext_vector_type(16))) float f32x16;
typedef __attribute__((ext_vector_type(8))) short bf16x8;
typedef __attribute__((ext_vector_type(8))) unsigned short u16x8;

__device__ __forceinline__ float bf2f(unsigned short u) {
    return __uint_as_float(((unsigned int)u) << 16);
}
__device__ __forceinline__ unsigned short f2bf(float f) {
    unsigned int u = __float_as_uint(f);
    return (unsigned short)((u + 0x7FFFu + ((u >> 16) & 1u)) >> 16);  // RNE
}
__device__ __forceinline__ void gload_lds16(const unsigned short* g, unsigned short* l) {
    __builtin_amdgcn_global_load_lds(
        (const __attribute__((address_space(1))) void*)g,
        (__attribute__((address_space(3))) void*)l, 16, 0, 0);
}

// ---------------- fp32 -> bf16 elementwise ----------------
__global__ __launch_bounds__(256) void cvt_f32_bf16(const float4* __restrict__ in,
                                                    ushort4* __restrict__ out, int n4) {
    int i = blockIdx.x * 256 + threadIdx.x;
    if (i < n4) {
        float4 v = in[i];
        ushort4 o;
        o.x = f2bf(v.x); o.y = f2bf(v.y); o.z = f2bf(v.z); o.w = f2bf(v.w);
        out[i] = o;
    }
}

// ---------------- transpose + convert: W[K][N] f32 -> WT[N][K] bf16 ----------------
__global__ __launch_bounds__(256) void transcvt(const float* __restrict__ W,
                                                unsigned short* __restrict__ WT,
                                                int K, int N) {
    __shared__ float tile[32][33];
    const int n0 = blockIdx.x * 32, k0 = blockIdx.y * 32;
    const int tx = threadIdx.x & 31, ty = threadIdx.x >> 5;  // ty 0..7
    #pragma unroll
    for (int r = 0; r < 32; r += 8)
        tile[ty + r][tx] = W[(size_t)(k0 + ty + r) * N + n0 + tx];
    __syncthreads();
    #pragma unroll
    for (int r = 0; r < 32; r += 8)
        WT[(size_t)(n0 + ty + r) * K + k0 + tx] = f2bf(tile[tx][ty + r]);
}

// ---------------- 256x256 8-phase bf16 MFMA GEMM: C = A @ BT^T + bias ----------------
#define GBAR() __builtin_amdgcn_s_barrier()
#define LGKM0() do { asm volatile("s_waitcnt lgkmcnt(0)" ::: "memory"); \
                     __builtin_amdgcn_sched_barrier(0); } while (0)

#define MFMA_PAIR(q, ni) \
    acc[(q)*2+0][ni] = __builtin_amdgcn_mfma_f32_16x16x32_bf16(a[0][0], breg[ni][0], acc[(q)*2+0][ni], 0, 0, 0); \
    acc[(q)*2+0][ni] = __builtin_amdgcn_mfma_f32_16x16x32_bf16(a[0][1], breg[ni][1], acc[(q)*2+0][ni], 0, 0, 0); \
    acc[(q)*2+1][ni] = __builtin_amdgcn_mfma_f32_16x16x32_bf16(a[1][0], breg[ni][0], acc[(q)*2+1][ni], 0, 0, 0); \
    acc[(q)*2+1][ni] = __builtin_amdgcn_mfma_f32_16x16x32_bf16(a[1][1], breg[ni][1], acc[(q)*2+1][ni], 0, 0, 0);

#define MFMA_Q(q) do { \
    __builtin_amdgcn_s_setprio(1); \
    MFMA_PAIR(q, 0) MFMA_PAIR(q, 1) MFMA_PAIR(q, 2) MFMA_PAIR(q, 3) \
    __builtin_amdgcn_s_setprio(0); } while (0)

#define LOAD_A(q) do { \
    a[0][0] = *(const bf16x8*)(pA + ((q)*2+0)*1024 + sw0); \
    a[0][1] = *(const bf16x8*)(pA + ((q)*2+0)*1024 + sw1); \
    a[1][0] = *(const bf16x8*)(pA + ((q)*2+1)*1024 + sw0); \
    a[1][1] = *(const bf16x8*)(pA + ((q)*2+1)*1024 + sw1); } while (0)

template<typename OutT>
__global__ __launch_bounds__(512, 2) void gemm256(
    const unsigned short* __restrict__ A, const unsigned short* __restrict__ BT,
    const float* __restrict__ bias, OutT* __restrict__ C,
    int M, int N, int K, int ntn)
{
    __shared__ __align__(16) unsigned short smem[65536];   // 128 KiB arena
    unsigned short* sAb = smem;
    unsigned short* sBb = smem + 32768;

    const int nwg = gridDim.x;
    const int wg  = blockIdx.x;
    const int swzb = (wg & 7) * (nwg >> 3) + (wg >> 3);   // bijective: nwg % 8 == 0
    const int m0 = (swzb / ntn) * 256, n0 = (swzb % ntn) * 256;

    const int t    = threadIdx.x;
    const int w    = t >> 6;
    const int lane = t & 63;
    const int wm   = w >> 2, wn = w & 3;

    const int srow8 = lane >> 3;
    const int sgch  = (lane & 7) ^ srow8;     // pre-swizzled global k-chunk
    const int NT    = K >> 6;                 // K-tiles of 64

    auto STAGE_A = [&](int ts, int cb) {
        const int r = cb + (w << 3);
        gload_lds16(A + (size_t)(m0 + r + srow8) * K + (ts << 6) + sgch * 8,
                    sAb + (size_t)(ts & 1) * 16384 + r * 64);
    };
    auto STAGE_B = [&](int ts, int cb) {
        const int r = cb + (w << 3);
        gload_lds16(BT + (size_t)(n0 + r + srow8) * K + (ts << 6) + sgch * 8,
                    sBb + (size_t)(ts & 1) * 16384 + r * 64);
    };

    const int frA = wm * 128 + (lane & 15);
    const int frB = wn * 64  + (lane & 15);
    const int sw0 = (((lane >> 4) + 0) ^ (lane & 7)) * 8;
    const int sw1 = (((lane >> 4) + 4) ^ (lane & 7)) * 8;

    f32x4 acc[8][4];
    #pragma unroll
    for (int i = 0; i < 8; ++i)
        #pragma unroll
        for (int j = 0; j < 4; ++j) acc[i][j] = (f32x4){0.f, 0.f, 0.f, 0.f};

    // ---- prologue ----
    STAGE_B(0, 0); STAGE_B(0, 64); STAGE_B(0, 128); STAGE_B(0, 192);
    STAGE_A(0, 0); STAGE_A(0, 64); STAGE_A(0, 128); STAGE_A(0, 192);
    asm volatile("s_waitcnt vmcnt(4)" ::: "memory");
    if (NT > 1) {
        STAGE_B(1, 0); STAGE_B(1, 64); STAGE_B(1, 128); STAGE_B(1, 192);
        STAGE_A(1, 0); STAGE_A(1, 128);
        asm volatile("s_waitcnt vmcnt(6)" ::: "memory");
    } else {
        asm volatile("s_waitcnt vmcnt(0)" ::: "memory");
    }
    GBAR();

    for (int ts = 0; ts < NT; ++ts) {
        const unsigned short* pA = sAb + (size_t)(ts & 1) * 16384 + frA * 64;
        const unsigned short* pB = sBb + (size_t)(ts & 1) * 16384 + frB * 64;
        bf16x8 breg[4][2];
        bf16x8 a[2][2];

        // ---- phase 1: B->regs + A-q0; stage A-hi(ts+1) ----
        #pragma unroll
        for (int ni = 0; ni < 4; ++ni) {
            breg[ni][0] = *(const bf16x8*)(pB + ni * 1024 + sw0);
            breg[ni][1] = *(const bf16x8*)(pB + ni * 1024 + sw1);
        }
        LOAD_A(0);
        if (ts + 1 < NT) { STAGE_A(ts + 1, 64); STAGE_A(ts + 1, 192); }
        GBAR(); LGKM0(); MFMA_Q(0); GBAR();

        // ---- phase 2: A-q1; stage B-lo(ts+2) ----
        LOAD_A(1);
        if (ts + 2 < NT) { STAGE_B(ts + 2, 0); STAGE_B(ts + 2, 64); }
        GBAR(); LGKM0(); MFMA_Q(1); GBAR();

        // ---- phase 3: A-q2; stage B-hi(ts+2) ----
        LOAD_A(2);
        if (ts + 2 < NT) { STAGE_B(ts + 2, 128); STAGE_B(ts + 2, 192); }
        GBAR(); LGKM0(); MFMA_Q(2); GBAR();

        // ---- phase 4: A-q3; stage A-lo(ts+2); counted vmcnt ----
        LOAD_A(3);
        if (ts + 2 < NT) { STAGE_A(ts + 2, 0); STAGE_A(ts + 2, 128); }
        GBAR(); LGKM0(); MFMA_Q(3);
        if (ts + 2 < NT) asm volatile("s_waitcnt vmcnt(6)" ::: "memory");
        else             asm volatile("s_waitcnt vmcnt(0)" ::: "memory");
        GBAR();
    }

    // ---- epilogue: LDS-bounce for coalesced wide stores ----
    if constexpr (sizeof(OutT) == 2) {
        unsigned short (*cb)[256] = (unsigned short (*)[256])smem;
        #pragma unroll
        for (int ni = 0; ni < 4; ++ni) {
            const int col = wn * 64 + ni * 16 + (lane & 15);
            const float bv = bias[n0 + col];
            #pragma unroll
            for (int mi = 0; mi < 8; ++mi) {
                const int rb = wm * 128 + mi * 16 + ((lane >> 4) << 2);
                #pragma unroll
                for (int r = 0; r < 4; ++r)
                    cb[rb + r][col] = f2bf(acc[mi][ni][r] + bv);
            }
        }
        __syncthreads();
        unsigned short* Cp = (unsigned short*)C;
        #pragma unroll
        for (int it = 0; it < 16; ++it) {
            const int row = it * 16 + (t >> 5);
            const int cs  = (t & 31) * 8;
            u16x8 v = *(const u16x8*)&cb[row][cs];
            *(u16x8*)(Cp + (size_t)(m0 + row) * N + n0 + cs) = v;
        }
    } else {
        float (*cf)[256] = (float (*)[256])smem;
        #pragma unroll
        for (int h = 0; h < 2; ++h) {
            if (wm == h) {
                #pragma unroll
                for (int ni = 0; ni < 4; ++ni) {
                    const int col = wn * 64 + ni * 16 + (lane & 15);
                    const float bv = bias[n0 + col];
                    #pragma unroll
                    for (int mi = 0; mi < 8; ++mi) {
                        const int rb = mi * 16 + ((lane >> 4) << 2);  // 0..127
                        #pragma unroll
                        for (int r = 0; r < 4; ++r)
                            cf[rb + r][col] = acc[mi][ni][r] + bv;
                    }
                }
            }
            __syncthreads();
            float* Cp = (float*)C;
            #pragma unroll
            for (int it = 0; it < 16; ++it) {
                const int row = it * 8 + (t >> 6);     // 0..127
                const int c4  = (t & 63) * 4;
                float4 v = *(const float4*)&cf[row][c4];
                *(float4*)(Cp + (size_t)(m0 + h * 128 + row) * N + n0 + c4) = v;
            }
            __syncthreads();
        }
    }
}

// ---------------- column attention, MFMA QK^T (bf16 in, bf16 out) ----------------
// One block per (b, bl). L = NB = 32 over block axis, D = 1024, causal.
// 4 waves split K=1024 for QK^T via mfma_32x32x16; LDS reduce; serial softmax; VALU PV.
__global__ __launch_bounds__(256) void col_attn_mfma(const unsigned short* __restrict__ qkv,
                                                     unsigned short* __restrict__ outb)
{
    const int b  = blockIdx.x >> 7;
    const int bl = blockIdx.x & (BL - 1);

    __shared__ float red[4][32][33];
    __shared__ float p_s[NB][NB + 1];

    const int t    = threadIdx.x;
    const int w    = t >> 6;
    const int lane = t & 63;

    const size_t rowstride = (size_t)BL * 3 * DD;
    const unsigned short* base = qkv + ((size_t)b * NB * BL + bl) * (3 * DD);

    // ---- QK^T: wave w covers k in [w*256, w*256+256), 16 MFMA steps ----
    // A-frag (Q): row = lane&31, k = (lane>>5)*8 + step*16
    // B-frag (K): col = lane&31 (K attention-row), same k pattern
    {
        const int arow = lane & 31;
        const int khi  = (lane >> 5) * 8;
        const unsigned short* qp = base + (size_t)arow * rowstride + w * 256 + khi;
        const unsigned short* kp = qp + DD;

        f32x16 acc0 = {}, acc1 = {};
        #pragma unroll
        for (int s = 0; s < 16; s += 2) {
            bf16x8 aq0 = *(const bf16x8*)(qp + s * 16);
            bf16x8 bk0 = *(const bf16x8*)(kp + s * 16);
            bf16x8 aq1 = *(const bf16x8*)(qp + s * 16 + 16);
            bf16x8 bk1 = *(const bf16x8*)(kp + s * 16 + 16);
            acc0 = __builtin_amdgcn_mfma_f32_32x32x16_bf16(aq0, bk0, acc0, 0, 0, 0);
            acc1 = __builtin_amdgcn_mfma_f32_32x32x16_bf16(aq1, bk1, acc1, 0, 0, 0);
        }
        // C/D layout: col = lane&31, row = (reg&3) + 8*(reg>>2) + 4*(lane>>5)
        const int ccol = lane & 31;
        const int rhi  = (lane >> 5) * 4;
        #pragma unroll
        for (int r = 0; r < 16; ++r) {
            const int crow = (r & 3) + 8 * (r >> 2) + rhi;
            red[w][crow][ccol] = acc0[r] + acc1[r];
        }
    }
    __syncthreads();

    // ---- reduce 4 waves -> p_s, apply scale ----
    {
        const float scale = 1.0f / 32.0f;   // 1/sqrt(1024)
        const int row = t >> 3;
        const int c0  = (t & 7) * 4;
        #pragma unroll
        for (int j = 0; j < 4; ++j) {
            const int c = c0 + j;
            p_s[row][c] = (red[0][row][c] + red[1][row][c] +
                           red[2][row][c] + red[3][row][c]) * scale;
        }
    }
    __syncthreads();

    // ---- causal softmax (rows on lanes 0..31; tiny) ----
    if (t < NB) {
        const int i = t;
        float mx = p_s[i][0];
        for (int j = 1; j <= i; ++j) mx = fmaxf(mx, p_s[i][j]);
        float sum = 0.f;
        for (int j = 0; j <= i; ++j) { float e = __expf(p_s[i][j] - mx); p_s[i][j] = e; sum += e; }
        const float inv = 1.0f / sum;
        for (int j = 0; j <= i; ++j) p_s[i][j] *= inv;
        for (int j = i + 1; j < NB; ++j) p_s[i][j] = 0.f;
    }
    __syncthreads();

    // ---- PV: thread owns 4 consecutive d for 8 rows per pass (coalesced V reads) ----
    const int d0v = t * 4;
    const unsigned short* vbase = base + 2 * DD;
    #pragma unroll 1
    for (int p = 0; p < 4; ++p) {
        float4 acc[8];
        #pragma unroll
        for (int ii = 0; ii < 8; ++ii) acc[ii] = make_float4(0.f, 0.f, 0.f, 0.f);
        const int jmax = (p + 1) * 8;
        for (int j = 0; j < jmax; ++j) {
            ushort4 v4 = *(const ushort4*)(vbase + (size_t)j * rowstride + d0v);
            const float vx = bf2f(v4.x), vy = bf2f(v4.y), vz = bf2f(v4.z), vw = bf2f(v4.w);
            #pragma unroll
            for (int ii = 0; ii < 8; ++ii) {
                const float pij = p_s[p * 8 + ii][j];
                acc[ii].x += pij * vx;
                acc[ii].y += pij * vy;
                acc[ii].z += pij * vz;
                acc[ii].w += pij * vw;
            }
        }
        #pragma unroll
        for (int ii = 0; ii < 8; ++ii) {
            const int i = p * 8 + ii;
            ushort4 o;
            o.x = f2bf(acc[ii].x); o.y = f2bf(acc[ii].y);
            o.z = f2bf(acc[ii].z); o.w = f2bf(acc[ii].w);
            *(ushort4*)(outb + ((size_t)(b * NB + i) * BL + bl) * DD + d0v) = o;
        }
    }
}

extern "C" void kernel_launch(void* const* d_in, const int* in_sizes, int n_in,
                              void* d_out, int out_size, void* d_ws, size_t ws_size,
                              hipStream_t stream) {
    (void)in_sizes; (void)n_in; (void)out_size; (void)ws_size;
    const float* x    = (const float*)d_in[0];
    const float* Wqkv = (const float*)d_in[1];
    const float* bqkv = (const float*)d_in[2];
    const float* Wout = (const float*)d_in[3];
    const float* bout = (const float*)d_in[4];
    float* out = (float*)d_out;

    char* ws = (char*)d_ws;
    unsigned short* xb    = (unsigned short*)ws;                        // 32 MiB
    unsigned short* WqkvT = (unsigned short*)(ws + ((size_t)32 << 20)); //  6 MiB
    unsigned short* WoutT = (unsigned short*)(ws + ((size_t)38 << 20)); //  2 MiB
    unsigned short* qkvb  = (unsigned short*)(ws + ((size_t)40 << 20)); // 96 MiB
    unsigned short* attnb = (unsigned short*)(ws + ((size_t)136 << 20));// 32 MiB

    const int M = BB * SS;  // 16384

    cvt_f32_bf16<<<dim3((M * DD / 4 + 255) / 256), dim3(256), 0, stream>>>(
        (const float4*)x, (ushort4*)xb, M * DD / 4);
    transcvt<<<dim3(3 * DD / 32, DD / 32), dim3(256), 0, stream>>>(Wqkv, WqkvT, DD, 3 * DD);
    transcvt<<<dim3(DD / 32, DD / 32), dim3(256), 0, stream>>>(Wout, WoutT, DD, DD);

    // QKV = x @ Wqkv + bqkv  (bf16 out): grid 64 x 12 = 768 tiles
    gemm256<unsigned short><<<dim3((M / 256) * (3 * DD / 256)), dim3(512), 0, stream>>>(
        xb, WqkvT, bqkv, qkvb, M, 3 * DD, DD, 3 * DD / 256);

    col_attn_mfma<<<dim3(BB * BL), dim3(256), 0, stream>>>(qkvb, attnb);

    // out = attn @ Wout + bout  (fp32 out): grid 64 x 4 = 256 tiles
    gemm256<float><<<dim3((M / 256) * (DD / 256)), dim3(512), 0, stream>>>(
        attnb, WoutT, bout, out, M, DD, DD, DD / 256);
}